// Round 1
// baseline (133.598 us; speedup 1.0000x reference)
//
#include <hip/hip_runtime.h>

// SelfAttentionPool (SAGPool-style), fully fused: one block per graph.
// N=100000 nodes, F=128, B=1000 graphs x 100 nodes, E=1.6M intra-graph edges,
// keep 80 nodes/graph.
//
// Factorization: z = (agg @ theta) == scatter of s[src]*dis[src]*dis[dst]
// where s[i] = x[i].theta  -> never materialize the (N,128) aggregation.
//
// Output layout (all float32): x_new (80000*128) | edge_row0 (E) | edge_row1 (E)
// | batch_new (80000).

#define NPG   100
#define EPG   1600     // NPG * DEG
#define KNUM  80
#define FDIM  128

__global__ __launch_bounds__(256)
void sagpool_fused(const float* __restrict__ x,
                   const int*   __restrict__ ei,
                   const float* __restrict__ theta,
                   float* __restrict__ out,
                   int E_total, int out_x_elems)
{
    const int g    = blockIdx.x;
    const int tid  = threadIdx.x;
    const int wave = tid >> 6;
    const int lane = tid & 63;
    const int base = g * NPG;

    __shared__ float  sh_theta[FDIM];
    __shared__ int    sh_src[EPG];
    __shared__ int    sh_dst[EPG];
    __shared__ int    sh_deg[NPG];
    __shared__ double sh_dis[NPG];      // 1/sqrt(deg), double for z accuracy
    __shared__ double sh_s[NPG];        // x[i] . theta
    __shared__ double sh_z[NPG];        // attention score
    __shared__ int    sh_kept[NPG];
    __shared__ int    sh_newid[NPG];
    __shared__ int    sh_keepnode[KNUM];
    __shared__ float  sh_scale[KNUM];

    if (tid < FDIM) sh_theta[tid] = theta[tid];
    if (tid < NPG)  sh_deg[tid] = 1;          // self-loop
    __syncthreads();

    // Load this graph's edges into LDS + degree histogram over src (row).
    for (int j = tid; j < EPG; j += 256) {
        int s = ei[g * EPG + j]           - base;
        int d = ei[E_total + g * EPG + j] - base;
        sh_src[j] = s;
        sh_dst[j] = d;
        atomicAdd(&sh_deg[s], 1);
    }
    __syncthreads();

    if (tid < NPG) sh_dis[tid] = 1.0 / sqrt((double)sh_deg[tid]);

    // s[i] = x[i] . theta  — one wave per node, float2 coalesced loads,
    // 64-lane shuffle reduction in double.
    const double th0 = (double)sh_theta[2 * lane];
    const double th1 = (double)sh_theta[2 * lane + 1];
    for (int n = wave; n < NPG; n += 4) {
        float2 xv = ((const float2*)(x + (size_t)(base + n) * FDIM))[lane];
        double p = (double)xv.x * th0 + (double)xv.y * th1;
        #pragma unroll
        for (int off = 32; off > 0; off >>= 1)
            p += __shfl_down(p, off, 64);
        if (lane == 0) sh_s[n] = p;
    }
    __syncthreads();

    // self-loop contribution, then edge scatter (scalar, LDS double atomics)
    if (tid < NPG) sh_z[tid] = sh_s[tid] * sh_dis[tid] * sh_dis[tid];
    __syncthreads();

    for (int j = tid; j < EPG; j += 256) {
        int s = sh_src[j], d = sh_dst[j];
        atomicAdd(&sh_z[d], sh_s[s] * sh_dis[s] * sh_dis[d]);
    }
    __syncthreads();

    // top-k by rank: rank = #{j : z[j] > z[i]} + #{j : z[j]==z[i], j<i}
    // (matches jax.lax.top_k tie-breaking: lower index first)
    if (tid < NPG) {
        double zi = sh_z[tid];
        int rank = 0;
        for (int j = 0; j < NPG; ++j) {
            double zj = sh_z[j];
            rank += (int)((zj > zi) | ((zj == zi) & (j < tid)));
        }
        sh_kept[tid] = (rank < KNUM) ? 1 : 0;
    }
    __syncthreads();

    // prefix-sum relabel (kept nodes in index order == sorted positions)
    if (tid < NPG) {
        int r = 0;
        for (int j = 0; j < tid; ++j) r += sh_kept[j];
        if (sh_kept[tid]) {
            int row = g * KNUM + r;
            sh_newid[tid]  = row;
            sh_keepnode[r] = tid;
            sh_scale[r]    = (float)(1.0 / (1.0 + exp(-sh_z[tid])));
            out[(size_t)out_x_elems + 2 * (size_t)E_total + row] = (float)g; // batch_new
        } else {
            sh_newid[tid] = -1;
        }
    }
    __syncthreads();

    // x_new[row] = x[kept] * sigmoid(z) — rows just read above, L2/LLC-hot
    for (int r = wave; r < KNUM; r += 4) {
        int   node = base + sh_keepnode[r];
        float sc   = sh_scale[r];
        float2 xv  = ((const float2*)(x + (size_t)node * FDIM))[lane];
        float2 o;
        o.x = xv.x * sc;
        o.y = xv.y * sc;
        ((float2*)(out + (size_t)(g * KNUM + r) * FDIM))[lane] = o;
    }

    // edge relabel; dropped edges -> (-1,-1)
    float* out_e0 = out + out_x_elems;
    float* out_e1 = out_e0 + E_total;
    for (int j = tid; j < EPG; j += 256) {
        int a = sh_newid[sh_src[j]];
        int b = sh_newid[sh_dst[j]];
        bool valid = (a >= 0) && (b >= 0);
        out_e0[g * EPG + j] = valid ? (float)a : -1.0f;
        out_e1[g * EPG + j] = valid ? (float)b : -1.0f;
    }
}

extern "C" void kernel_launch(void* const* d_in, const int* in_sizes, int n_in,
                              void* d_out, int out_size, void* d_ws, size_t ws_size,
                              hipStream_t stream)
{
    const float* x     = (const float*)d_in[0];
    const int*   ei    = (const int*)d_in[1];
    // d_in[2] (batch) unused: batch_new[row] == graph id by construction
    const float* theta = (const float*)d_in[3];
    float* out = (float*)d_out;

    const int N = in_sizes[0] / FDIM;        // 100000
    const int E = in_sizes[1] / 2;           // 1600000
    const int B = N / NPG;                   // 1000
    const int out_x_elems = B * KNUM * FDIM; // 10,240,000

    sagpool_fused<<<dim3(B), dim3(256), 0, stream>>>(x, ei, theta, out, E, out_x_elems);
}